// Round 1
// baseline (248.806 us; speedup 1.0000x reference)
//
#include <hip/hip_runtime.h>
#include <hip/hip_bf16.h>
#include <math.h>

typedef __bf16 bf16x8 __attribute__((ext_vector_type(8)));
typedef float f32x4 __attribute__((ext_vector_type(4)));
typedef unsigned short u16x8 __attribute__((ext_vector_type(8)));
typedef unsigned short u16x4 __attribute__((ext_vector_type(4)));

// ---- problem constants ----
// T=1024, B=4, H=16, D=64, E=1024, M = T*B = 4096 (row m = t*4 + b)

// ws layout, element offsets (ushort elements)
#define OFF_XQ   0u          // 4096x1024 bf16
#define OFF_XK   4194304u
#define OFF_XV   8388608u
#define OFF_WQ   12582912u   // 1024x1024 bf16
#define OFF_WK   13631488u
#define OFF_WV   14680064u
#define OFF_WO   15728640u
#define OFF_QR   16777216u   // [b][h][t][d] bf16 (rope'd)
#define OFF_KR   20971520u
#define OFF_VROW 25165824u   // [b][h][t][d] bf16
#define OFF_VT   29360128u   // [b][h][d][t] bf16
#define OFF_AO   33554432u   // [m=q*4+b][e=h*64+d] bf16
// total 36M ushorts = 72 MB

static __device__ __forceinline__ unsigned short f2bf(float f){
  unsigned u = __builtin_bit_cast(unsigned, f);
  u += 0x7FFFu + ((u >> 16) & 1u);           // RNE
  return (unsigned short)(u >> 16);
}

static __device__ __forceinline__ f32x4 mfma16(bf16x8 a, bf16x8 b, f32x4 c){
  return __builtin_amdgcn_mfma_f32_16x16x32_bf16(a, b, c, 0, 0, 0);
}

// -------- fp32 -> bf16 conversion of all inputs into ws (contiguous) --------
__global__ __launch_bounds__(256) void cvt_all(
    const float* __restrict__ q, const float* __restrict__ k, const float* __restrict__ v,
    const float* __restrict__ qw, const float* __restrict__ kw, const float* __restrict__ vw,
    const float* __restrict__ ow, unsigned short* __restrict__ ws)
{
  size_t e = ((size_t)blockIdx.x * 256 + threadIdx.x) * 4;
  const float* s;
  if      (e < 4194304u)  { s = q  + e; }
  else if (e < 8388608u)  { s = k  + (e - 4194304u); }
  else if (e < 12582912u) { s = v  + (e - 8388608u); }
  else if (e < 13631488u) { s = qw + (e - 12582912u); }
  else if (e < 14680064u) { s = kw + (e - 13631488u); }
  else if (e < 15728640u) { s = vw + (e - 14680064u); }
  else                    { s = ow + (e - 15728640u); }
  float4 f = *(const float4*)s;
  u16x4 o;
  o[0] = f2bf(f.x); o[1] = f2bf(f.y); o[2] = f2bf(f.z); o[3] = f2bf(f.w);
  *(u16x4*)(ws + e) = o;
}

// -------- GEMM: C[m][n] = sum_k A[m][k] * W[n][k]   (M=4096, N=1024, K=1024) --------
// mode 0: outF[m*1024+n] = acc (fp32)
// mode 1: RoPE epilogue -> outB bf16 at [b][h][t][d]   (b = m&3, t = m>>2, h = n>>6, d = n&63)
// mode 2: plain bf16   -> outB at [b][h][t][d]
__global__ __launch_bounds__(256) void gemm_bt(
    const unsigned short* __restrict__ A, const unsigned short* __restrict__ W,
    float* __restrict__ outF, unsigned short* __restrict__ outB, int mode)
{
  const int tid = threadIdx.x;
  const int lane = tid & 63, wave = tid >> 6;
  const int wr = wave >> 1, wc = wave & 1;
  const int l16 = lane & 15, lg = lane >> 4;
  const int m0 = blockIdx.y * 128, n0 = blockIdx.x * 128;

  __shared__ unsigned short As[128*32];
  __shared__ unsigned short Bs[128*32];

  f32x4 acc[4][4];
#pragma unroll
  for (int i = 0; i < 4; ++i)
#pragma unroll
    for (int j = 0; j < 4; ++j)
      acc[i][j] = (f32x4){0.f, 0.f, 0.f, 0.f};

  const int r0 = tid >> 2;           // 0..63
  const int c0 = (tid & 3) * 8;      // 0,8,16,24
  const unsigned short* Ap = A + (size_t)(m0 + r0) * 1024 + c0;
  const unsigned short* Wp = W + (size_t)(n0 + r0) * 1024 + c0;

  for (int kt = 0; kt < 32; ++kt){
    u16x8 a0 = *(const u16x8*)(Ap + kt*32);
    u16x8 a1 = *(const u16x8*)(Ap + 64*1024 + kt*32);
    u16x8 b0 = *(const u16x8*)(Wp + kt*32);
    u16x8 b1 = *(const u16x8*)(Wp + 64*1024 + kt*32);
    __syncthreads();
    *(u16x8*)&As[r0*32 + c0]        = a0;
    *(u16x8*)&As[(r0 + 64)*32 + c0] = a1;
    *(u16x8*)&Bs[r0*32 + c0]        = b0;
    *(u16x8*)&Bs[(r0 + 64)*32 + c0] = b1;
    __syncthreads();
    bf16x8 af[4], bfr[4];
#pragma unroll
    for (int mt = 0; mt < 4; ++mt) af[mt]  = *(const bf16x8*)&As[(wr*64 + mt*16 + l16)*32 + lg*8];
#pragma unroll
    for (int nt = 0; nt < 4; ++nt) bfr[nt] = *(const bf16x8*)&Bs[(wc*64 + nt*16 + l16)*32 + lg*8];
#pragma unroll
    for (int mt = 0; mt < 4; ++mt)
#pragma unroll
      for (int nt = 0; nt < 4; ++nt)
        acc[mt][nt] = mfma16(af[mt], bfr[nt], acc[mt][nt]);
  }

  if (mode == 0){
#pragma unroll
    for (int mt = 0; mt < 4; ++mt)
#pragma unroll
      for (int nt = 0; nt < 4; ++nt)
#pragma unroll
        for (int r = 0; r < 4; ++r){
          int m = m0 + wr*64 + mt*16 + lg*4 + r;
          int n = n0 + wc*64 + nt*16 + l16;
          outF[(size_t)m*1024 + n] = acc[mt][nt][r];
        }
  } else if (mode == 2){
#pragma unroll
    for (int mt = 0; mt < 4; ++mt)
#pragma unroll
      for (int nt = 0; nt < 4; ++nt)
#pragma unroll
        for (int r = 0; r < 4; ++r){
          int m = m0 + wr*64 + mt*16 + lg*4 + r;
          int n = n0 + wc*64 + nt*16 + l16;
          int t = m >> 2, bi = m & 3, h = n >> 6, d = n & 63;
          outB[(((size_t)(bi*16 + h))*1024 + t)*64 + d] = f2bf(acc[mt][nt][r]);
        }
  } else { // mode 1: RoPE.  acc pair (nt, nt+2) holds (x1, x2) for d and d+32.
#pragma unroll
    for (int mt = 0; mt < 4; ++mt){
      int mbase = m0 + wr*64 + mt*16 + lg*4;   // multiple of 4 -> b = r, t fixed
      int t = mbase >> 2;
#pragma unroll
      for (int nt = 0; nt < 2; ++nt){
        int n = n0 + wc*64 + nt*16 + l16;
        int h = n >> 6, d = n & 31;
        float theta = expf((float)d * -0.28782313662425575f);  // -ln(10000)/32
        float ang = (float)t * theta;
        float sv = sinf(ang), cv = cosf(ang);
#pragma unroll
        for (int r = 0; r < 4; ++r){
          float x1 = acc[mt][nt][r];
          float x2 = acc[mt][nt + 2][r];
          float o1 = x1*cv - x2*sv;
          float o2 = x1*sv + x2*cv;
          size_t ob = (((size_t)(r*16 + h))*1024 + t)*64;   // b = r
          outB[ob + d]      = f2bf(o1);
          outB[ob + d + 32] = f2bf(o2);
        }
      }
    }
  }
}

// -------- V transpose per head: Vrow[b][h][t][d] -> Vt[b][h][d][t] --------
__global__ __launch_bounds__(256) void vtrans(
    const unsigned short* __restrict__ Vrow, unsigned short* __restrict__ Vt)
{
  const int bh = blockIdx.y;
  const int t0 = blockIdx.x * 64;
  const unsigned short* src = Vrow + (size_t)bh*65536 + (size_t)t0*64;
  unsigned short* dst = Vt + (size_t)bh*65536 + t0;
  __shared__ unsigned short tile[64][65];
  const int tid = threadIdx.x;
#pragma unroll
  for (int i = 0; i < 16; ++i){
    int idx = tid + i*256;
    int r = idx >> 6, c = idx & 63;
    tile[r][c] = src[r*64 + c];
  }
  __syncthreads();
#pragma unroll
  for (int i = 0; i < 16; ++i){
    int idx = tid + i*256;
    int d = idx >> 6, c = idx & 63;
    dst[(size_t)d*1024 + c] = tile[c][d];
  }
}

// -------- flash attention: block = (128 q rows, one (b,h)); 4 waves x 32 q rows --------
__global__ __launch_bounds__(256) void attn_kernel(
    const unsigned short* __restrict__ Qr, const unsigned short* __restrict__ Kr,
    const unsigned short* __restrict__ Vt, const int* __restrict__ am,
    const int* __restrict__ kpm, unsigned short* __restrict__ AO)
{
  const int tid = threadIdx.x;
  const int lane = tid & 63, w = tid >> 6;
  const int l16 = lane & 15, lg = lane >> 4;
  const int bh = blockIdx.y, b = bh >> 4, h = bh & 15;
  const int q0 = blockIdx.x * 128 + w * 32;
  const size_t hb = (size_t)bh * 65536;

  __shared__ unsigned short Plds[4*2048];
  unsigned short* Pw = Plds + w*2048;

  bf16x8 qf[2][2];
#pragma unroll
  for (int mt = 0; mt < 2; ++mt)
#pragma unroll
    for (int kk = 0; kk < 2; ++kk)
      qf[mt][kk] = *(const bf16x8*)&Qr[hb + (size_t)(q0 + mt*16 + l16)*64 + kk*32 + lg*8];

  f32x4 O[2][4];
  float mst[2][4], lst[2][4];
#pragma unroll
  for (int mt = 0; mt < 2; ++mt){
#pragma unroll
    for (int nd = 0; nd < 4; ++nd) O[mt][nd] = (f32x4){0.f, 0.f, 0.f, 0.f};
#pragma unroll
    for (int r = 0; r < 4; ++r){ mst[mt][r] = -1e30f; lst[mt][r] = 0.f; }
  }

  for (int kt = 0; kt < 16; ++kt){
    const int kb = kt*64;
    // S = (Q K^T)
    f32x4 s[2][4];
#pragma unroll
    for (int nk = 0; nk < 4; ++nk){
      bf16x8 kf0 = *(const bf16x8*)&Kr[hb + (size_t)(kb + nk*16 + l16)*64 + lg*8];
      bf16x8 kf1 = *(const bf16x8*)&Kr[hb + (size_t)(kb + nk*16 + l16)*64 + 32 + lg*8];
#pragma unroll
      for (int mt = 0; mt < 2; ++mt){
        f32x4 t0 = (f32x4){0.f, 0.f, 0.f, 0.f};
        t0 = mfma16(qf[mt][0], kf0, t0);
        t0 = mfma16(qf[mt][1], kf1, t0);
        s[mt][nk] = t0;
      }
    }
    int kpv[4];
#pragma unroll
    for (int nk = 0; nk < 4; ++nk) kpv[nk] = kpm[b*1024 + kb + nk*16 + l16];

    // scale + mask + online softmax (wave-parallel: reduce over 16-lane group)
#pragma unroll
    for (int mt = 0; mt < 2; ++mt){
#pragma unroll
      for (int r = 0; r < 4; ++r){
        const int q = q0 + mt*16 + lg*4 + r;
        const int* amp = am + (size_t)(b*1024 + q)*1024 + kb;
        float mx = -1e30f;
#pragma unroll
        for (int nk = 0; nk < 4; ++nk){
          float val = s[mt][nk][r]*0.125f - 100000.0f*(float)(amp[nk*16 + l16] + kpv[nk]);
          s[mt][nk][r] = val;
          mx = fmaxf(mx, val);
        }
#pragma unroll
        for (int off = 1; off < 16; off <<= 1) mx = fmaxf(mx, __shfl_xor(mx, off, 64));
        float mo = mst[mt][r];
        float mn = fmaxf(mo, mx);
        float sf = __expf(mo - mn);
        mst[mt][r] = mn;
        float rs = 0.f;
#pragma unroll
        for (int nk = 0; nk < 4; ++nk){
          float p = __expf(s[mt][nk][r] - mn);
          s[mt][nk][r] = p;
          rs += p;
        }
#pragma unroll
        for (int off = 1; off < 16; off <<= 1) rs += __shfl_xor(rs, off, 64);
        lst[mt][r] = lst[mt][r]*sf + rs;
#pragma unroll
        for (int nd = 0; nd < 4; ++nd) O[mt][nd][r] *= sf;
      }
    }

    // P -> LDS (bf16), repack to A-operand layout
    __syncthreads();
#pragma unroll
    for (int mt = 0; mt < 2; ++mt)
#pragma unroll
      for (int nk = 0; nk < 4; ++nk)
#pragma unroll
        for (int r = 0; r < 4; ++r)
          Pw[(mt*16 + lg*4 + r)*64 + nk*16 + l16] = f2bf(s[mt][nk][r]);
    __syncthreads();

    // O += P V
    bf16x8 vf[4][2];
#pragma unroll
    for (int nd = 0; nd < 4; ++nd)
#pragma unroll
      for (int kk = 0; kk < 2; ++kk)
        vf[nd][kk] = *(const bf16x8*)&Vt[hb + (size_t)(nd*16 + l16)*1024 + kb + kk*32 + lg*8];
#pragma unroll
    for (int mt = 0; mt < 2; ++mt)
#pragma unroll
      for (int kk = 0; kk < 2; ++kk){
        bf16x8 pf = *(const bf16x8*)&Pw[(mt*16 + l16)*64 + kk*32 + lg*8];
#pragma unroll
        for (int nd = 0; nd < 4; ++nd)
          O[mt][nd] = mfma16(pf, vf[nd][kk], O[mt][nd]);
      }
  }

  // epilogue: O/l -> AO[(q*4+b)*1024 + h*64 + d] bf16
#pragma unroll
  for (int mt = 0; mt < 2; ++mt)
#pragma unroll
    for (int r = 0; r < 4; ++r){
      float inv = 1.0f / lst[mt][r];
      int q = q0 + mt*16 + lg*4 + r;
      size_t rowb = ((size_t)q*4 + b)*1024 + h*64;
#pragma unroll
      for (int nd = 0; nd < 4; ++nd)
        AO[rowb + nd*16 + l16] = f2bf(O[mt][nd][r]*inv);
    }
}

extern "C" void kernel_launch(void* const* d_in, const int* in_sizes, int n_in,
                              void* d_out, int out_size, void* d_ws, size_t ws_size,
                              hipStream_t stream)
{
  const float* q   = (const float*)d_in[0];
  const float* k   = (const float*)d_in[1];
  const float* v   = (const float*)d_in[2];
  const int*   kpm = (const int*)d_in[3];
  const int*   am  = (const int*)d_in[4];
  const float* qw  = (const float*)d_in[5];
  const float* kw  = (const float*)d_in[6];
  const float* vw  = (const float*)d_in[7];
  const float* ow  = (const float*)d_in[8];
  unsigned short* ws = (unsigned short*)d_ws;

  cvt_all<<<16384, 256, 0, stream>>>(q, k, v, qw, kw, vw, ow, ws);

  dim3 gg(8, 32);
  gemm_bt<<<gg, 256, 0, stream>>>(ws + OFF_XQ, ws + OFF_WQ, nullptr, ws + OFF_QR, 1);
  gemm_bt<<<gg, 256, 0, stream>>>(ws + OFF_XK, ws + OFF_WK, nullptr, ws + OFF_KR, 1);
  gemm_bt<<<gg, 256, 0, stream>>>(ws + OFF_XV, ws + OFF_WV, nullptr, ws + OFF_VROW, 2);
  vtrans<<<dim3(16, 64), 256, 0, stream>>>(ws + OFF_VROW, ws + OFF_VT);
  attn_kernel<<<dim3(8, 64), 256, 0, stream>>>(ws + OFF_QR, ws + OFF_KR, ws + OFF_VT,
                                               am, kpm, ws + OFF_AO);
  gemm_bt<<<gg, 256, 0, stream>>>(ws + OFF_AO, ws + OFF_WO, (float*)d_out, nullptr, 0);
}